// Round 1
// baseline (554.817 us; speedup 1.0000x reference)
//
#include <hip/hip_runtime.h>
#include <stdint.h>

#define MD 8192
#define ND 8192
#define KD 2048
#define KTH 15099494  // int(8192*2048*0.9)

typedef int v4i __attribute__((ext_vector_type(4)));

__device__ __forceinline__ void gload_lds16(const void* g, void* l) {
  __builtin_amdgcn_global_load_lds(
      (const __attribute__((address_space(1))) uint32_t*)g,
      (__attribute__((address_space(3))) uint32_t*)l, 16, 0, 0);
}

// ---------------- absmax reduction ----------------
__global__ void absmax_kernel(const float* __restrict__ x, int n4, unsigned int* out) {
  int tid = blockIdx.x * blockDim.x + threadIdx.x;
  int stride = gridDim.x * blockDim.x;
  const float4* p = (const float4*)x;
  float m = 0.f;
  for (int i = tid; i < n4; i += stride) {
    float4 v = p[i];
    m = fmaxf(m, fmaxf(fmaxf(fabsf(v.x), fabsf(v.y)), fmaxf(fabsf(v.z), fabsf(v.w))));
  }
  #pragma unroll
  for (int off = 32; off; off >>= 1) m = fmaxf(m, __shfl_down(m, off, 64));
  if ((threadIdx.x & 63) == 0) atomicMax(out, __float_as_uint(m));
}

// ---------------- quantize x1 (row-major keep) + histogram ----------------
__global__ void quant_hist_kernel(const float* __restrict__ x, int8_t* __restrict__ q,
                                  int n4, const unsigned int* sbits, unsigned int* hist) {
  __shared__ unsigned int h[256];
  for (int i = threadIdx.x; i < 256; i += blockDim.x) h[i] = 0;
  __syncthreads();
  float s = __uint_as_float(*sbits);
  int tid = blockIdx.x * blockDim.x + threadIdx.x;
  int stride = gridDim.x * blockDim.x;
  const float4* p = (const float4*)x;
  uint32_t* qo = (uint32_t*)q;
  for (int i = tid; i < n4; i += stride) {
    float4 v = p[i];
    int q0 = (int)rintf(v.x / s * 127.0f);
    int q1 = (int)rintf(v.y / s * 127.0f);
    int q2 = (int)rintf(v.z / s * 127.0f);
    int q3 = (int)rintf(v.w / s * 127.0f);
    atomicAdd(&h[q0 + 127], 1u);
    atomicAdd(&h[q1 + 127], 1u);
    atomicAdd(&h[q2 + 127], 1u);
    atomicAdd(&h[q3 + 127], 1u);
    uint32_t packed = (uint32_t)(uint8_t)(int8_t)q0 |
                      ((uint32_t)(uint8_t)(int8_t)q1 << 8) |
                      ((uint32_t)(uint8_t)(int8_t)q2 << 16) |
                      ((uint32_t)(uint8_t)(int8_t)q3 << 24);
    qo[i] = packed;
  }
  __syncthreads();
  for (int i = threadIdx.x; i < 256; i += blockDim.x)
    if (h[i]) atomicAdd(&hist[i], h[i]);
}

// ---------------- quantize x2 transposed ([K][N] -> q2t[N][K]) + histogram ----------------
#define TQS 80  // LDS row stride (bytes), 16-aligned, breaks bank patterns
__global__ void transq_kernel(const float* __restrict__ x, int8_t* __restrict__ qt,
                              const unsigned int* sbits, unsigned int* hist) {
  __shared__ __align__(16) int8_t tile[64 * TQS];
  __shared__ unsigned int h[256];
  for (int i = threadIdx.x; i < 256; i += blockDim.x) h[i] = 0;
  __syncthreads();
  float s = __uint_as_float(*sbits);
  int n0 = blockIdx.x * 64, k0 = blockIdx.y * 64;
  int t = threadIdx.x;
  #pragma unroll
  for (int j = 0; j < 4; ++j) {
    int idx = j * 256 + t;       // 0..1023
    int kr = idx >> 4;           // 0..63 (k within tile)
    int nc = (idx & 15) * 4;     // 0..60 (n within tile)
    float4 v = *(const float4*)(x + (size_t)(k0 + kr) * ND + n0 + nc);
    int q0 = (int)rintf(v.x / s * 127.0f);
    int q1 = (int)rintf(v.y / s * 127.0f);
    int q2 = (int)rintf(v.z / s * 127.0f);
    int q3 = (int)rintf(v.w / s * 127.0f);
    atomicAdd(&h[q0 + 127], 1u);
    atomicAdd(&h[q1 + 127], 1u);
    atomicAdd(&h[q2 + 127], 1u);
    atomicAdd(&h[q3 + 127], 1u);
    tile[(nc + 0) * TQS + kr] = (int8_t)q0;
    tile[(nc + 1) * TQS + kr] = (int8_t)q1;
    tile[(nc + 2) * TQS + kr] = (int8_t)q2;
    tile[(nc + 3) * TQS + kr] = (int8_t)q3;
  }
  __syncthreads();
  {
    int n = t >> 2, kc = (t & 3) * 16;
    uint4 val = *(const uint4*)(tile + n * TQS + kc);
    *(uint4*)(qt + (size_t)(n0 + n) * KD + k0 + kc) = val;
  }
  for (int i = threadIdx.x; i < 256; i += blockDim.x)
    if (h[i]) atomicAdd(&hist[i], h[i]);
}

// ---------------- kth-value from histograms ----------------
__global__ void finalize_kernel(const unsigned int* __restrict__ hist1,
                                const unsigned int* __restrict__ hist2,
                                float* __restrict__ out_k) {
  if (threadIdx.x == 0) {
    long long c = 0; int v = 127;
    for (int i = 0; i < 255; ++i) { c += hist1[i]; if (c >= KTH) { v = i - 127; break; } }
    out_k[0] = (float)v;
    c = 0; v = 127;
    for (int i = 0; i < 255; ++i) { c += hist2[i]; if (c >= KTH) { v = i - 127; break; } }
    out_k[1] = (float)v;
  }
}

// ---------------- i8 GEMM: C = q1[M][K] @ q2t[N][K]^T, scaled ----------------
// 128x128 tile, BK=128, 4 waves (2x2), each wave 64x64 via 4x4 of 16x16x64 i8 MFMA.
__global__ __launch_bounds__(256, 2) void gemm_i8_kernel(
    const int8_t* __restrict__ qa, const int8_t* __restrict__ qb,
    float* __restrict__ out, const unsigned int* __restrict__ sbits) {
  __shared__ __align__(16) int8_t Asm[128 * 128];
  __shared__ __align__(16) int8_t Bsm[128 * 128];

  // XCD-bijective swizzle: 4096 blocks % 8 == 0
  int bid = blockIdx.x;
  int swz = (bid & 7) * 512 + (bid >> 3);
  int brow = swz >> 6, bcol = swz & 63;

  int t = threadIdx.x;
  int lane = t & 63;
  int w = t >> 6;
  int wr = (w >> 1) * 64, wc = (w & 1) * 64;

  v4i acc[4][4] = {};

  const int8_t* ga = qa + (size_t)brow * 128 * KD;
  const int8_t* gb = qb + (size_t)bcol * 128 * KD;

  int srow = t >> 3;     // 0..31 (row within 32-row staging slab)
  int schunk = t & 7;    // swizzled 16B-chunk slot in LDS row

  for (int kt = 0; kt < KD / 128; ++kt) {
    int kbase = kt * 128;
    #pragma unroll
    for (int i = 0; i < 4; ++i) {
      int row = i * 32 + srow;
      int gchunk = schunk ^ (row & 7);  // pre-swizzled global source
      gload_lds16(ga + (size_t)row * KD + kbase + gchunk * 16, Asm + i * 4096 + t * 16);
    }
    #pragma unroll
    for (int i = 0; i < 4; ++i) {
      int row = i * 32 + srow;
      int gchunk = schunk ^ (row & 7);
      gload_lds16(gb + (size_t)row * KD + kbase + gchunk * 16, Bsm + i * 4096 + t * 16);
    }
    __syncthreads();
    #pragma unroll
    for (int kh = 0; kh < 2; ++kh) {
      v4i aF[4], bF[4];
      #pragma unroll
      for (int m = 0; m < 4; ++m) {
        int row = wr + m * 16 + (lane & 15);
        int chunk = (kh * 4 + (lane >> 4)) ^ (row & 7);
        aF[m] = *(const v4i*)(Asm + row * 128 + chunk * 16);
      }
      #pragma unroll
      for (int n = 0; n < 4; ++n) {
        int row = wc + n * 16 + (lane & 15);
        int chunk = (kh * 4 + (lane >> 4)) ^ (row & 7);
        bF[n] = *(const v4i*)(Bsm + row * 128 + chunk * 16);
      }
      #pragma unroll
      for (int m = 0; m < 4; ++m)
        #pragma unroll
        for (int n = 0; n < 4; ++n)
          acc[m][n] = __builtin_amdgcn_mfma_i32_16x16x64_i8(aF[m], bF[n], acc[m][n], 0, 0, 0);
    }
    __syncthreads();
  }

  float s1 = __uint_as_float(sbits[0]);
  float s2 = __uint_as_float(sbits[1]);
  float scale = s1 * s2 / (127.0f * 127.0f);
  int orow = brow * 128 + wr + ((lane >> 4) * 4);
  int ocol = bcol * 128 + wc + (lane & 15);
  #pragma unroll
  for (int m = 0; m < 4; ++m)
    #pragma unroll
    for (int n = 0; n < 4; ++n)
      #pragma unroll
      for (int r = 0; r < 4; ++r)
        out[(size_t)(orow + m * 16 + r) * ND + (ocol + n * 16)] = (float)acc[m][n][r] * scale;
}

extern "C" void kernel_launch(void* const* d_in, const int* in_sizes, int n_in,
                              void* d_out, int out_size, void* d_ws, size_t ws_size,
                              hipStream_t stream) {
  const float* x1 = (const float*)d_in[0];
  const float* x2 = (const float*)d_in[1];
  float* out = (float*)d_out;
  uint8_t* ws = (uint8_t*)d_ws;

  unsigned int* sbits = (unsigned int*)ws;                 // [0]=s1 bits, [1]=s2 bits
  unsigned int* hist1 = (unsigned int*)(ws + 256);
  unsigned int* hist2 = (unsigned int*)(ws + 256 + 1024);
  int8_t* q1  = (int8_t*)(ws + 4096);
  int8_t* q2t = q1 + (size_t)MD * KD;

  const int n4_1 = MD * KD / 4;  // 4,194,304 float4s
  const int n4_2 = KD * ND / 4;

  hipMemsetAsync(ws, 0, 4096, stream);
  absmax_kernel<<<2048, 256, 0, stream>>>(x1, n4_1, sbits + 0);
  absmax_kernel<<<2048, 256, 0, stream>>>(x2, n4_2, sbits + 1);
  quant_hist_kernel<<<2048, 256, 0, stream>>>(x1, q1, n4_1, sbits + 0, hist1);
  transq_kernel<<<dim3(ND / 64, KD / 64), 256, 0, stream>>>(x2, q2t, sbits + 1, hist2);
  finalize_kernel<<<1, 64, 0, stream>>>(hist1, hist2, out + (size_t)MD * ND);
  gemm_i8_kernel<<<4096, 256, 0, stream>>>(q1, q2t, out, sbits);
}

// Round 2
// 483.907 us; speedup vs baseline: 1.1465x; 1.1465x over previous
//
#include <hip/hip_runtime.h>
#include <stdint.h>

#define MD 8192
#define ND 8192
#define KD 2048
#define KTH 15099494  // int(8192*2048*0.9)

typedef int v4i __attribute__((ext_vector_type(4)));

__device__ __forceinline__ void gload_lds16(const void* g, void* l) {
  __builtin_amdgcn_global_load_lds(
      (const __attribute__((address_space(1))) uint32_t*)g,
      (__attribute__((address_space(3))) uint32_t*)l, 16, 0, 0);
}

// ---------------- absmax reduction ----------------
__global__ void absmax_kernel(const float* __restrict__ x, int n4, unsigned int* out) {
  int tid = blockIdx.x * blockDim.x + threadIdx.x;
  int stride = gridDim.x * blockDim.x;
  const float4* p = (const float4*)x;
  float m = 0.f;
  for (int i = tid; i < n4; i += stride) {
    float4 v = p[i];
    m = fmaxf(m, fmaxf(fmaxf(fabsf(v.x), fabsf(v.y)), fmaxf(fabsf(v.z), fabsf(v.w))));
  }
  #pragma unroll
  for (int off = 32; off; off >>= 1) m = fmaxf(m, __shfl_down(m, off, 64));
  if ((threadIdx.x & 63) == 0) atomicMax(out, __float_as_uint(m));
}

// ---------------- quantize x1 (row-major keep) + histogram ----------------
__global__ void quant_hist_kernel(const float* __restrict__ x, int8_t* __restrict__ q,
                                  int n4, const unsigned int* sbits, unsigned int* hist) {
  __shared__ unsigned int h[256];
  for (int i = threadIdx.x; i < 256; i += blockDim.x) h[i] = 0;
  __syncthreads();
  float s = __uint_as_float(*sbits);
  int tid = blockIdx.x * blockDim.x + threadIdx.x;
  int stride = gridDim.x * blockDim.x;
  const float4* p = (const float4*)x;
  uint32_t* qo = (uint32_t*)q;
  for (int i = tid; i < n4; i += stride) {
    float4 v = p[i];
    int q0 = (int)rintf(v.x / s * 127.0f);
    int q1 = (int)rintf(v.y / s * 127.0f);
    int q2 = (int)rintf(v.z / s * 127.0f);
    int q3 = (int)rintf(v.w / s * 127.0f);
    atomicAdd(&h[q0 + 127], 1u);
    atomicAdd(&h[q1 + 127], 1u);
    atomicAdd(&h[q2 + 127], 1u);
    atomicAdd(&h[q3 + 127], 1u);
    uint32_t packed = (uint32_t)(uint8_t)(int8_t)q0 |
                      ((uint32_t)(uint8_t)(int8_t)q1 << 8) |
                      ((uint32_t)(uint8_t)(int8_t)q2 << 16) |
                      ((uint32_t)(uint8_t)(int8_t)q3 << 24);
    qo[i] = packed;
  }
  __syncthreads();
  for (int i = threadIdx.x; i < 256; i += blockDim.x)
    if (h[i]) atomicAdd(&hist[i], h[i]);
}

// ---------------- quantize x2 transposed ([K][N] -> q2t[N][K]) + histogram ----------------
#define TQS 80  // LDS row stride (bytes), 16-aligned, breaks bank patterns
__global__ void transq_kernel(const float* __restrict__ x, int8_t* __restrict__ qt,
                              const unsigned int* sbits, unsigned int* hist) {
  __shared__ __align__(16) int8_t tile[64 * TQS];
  __shared__ unsigned int h[256];
  for (int i = threadIdx.x; i < 256; i += blockDim.x) h[i] = 0;
  __syncthreads();
  float s = __uint_as_float(*sbits);
  int n0 = blockIdx.x * 64, k0 = blockIdx.y * 64;
  int t = threadIdx.x;
  #pragma unroll
  for (int j = 0; j < 4; ++j) {
    int idx = j * 256 + t;       // 0..1023
    int kr = idx >> 4;           // 0..63 (k within tile)
    int nc = (idx & 15) * 4;     // 0..60 (n within tile)
    float4 v = *(const float4*)(x + (size_t)(k0 + kr) * ND + n0 + nc);
    int q0 = (int)rintf(v.x / s * 127.0f);
    int q1 = (int)rintf(v.y / s * 127.0f);
    int q2 = (int)rintf(v.z / s * 127.0f);
    int q3 = (int)rintf(v.w / s * 127.0f);
    atomicAdd(&h[q0 + 127], 1u);
    atomicAdd(&h[q1 + 127], 1u);
    atomicAdd(&h[q2 + 127], 1u);
    atomicAdd(&h[q3 + 127], 1u);
    tile[(nc + 0) * TQS + kr] = (int8_t)q0;
    tile[(nc + 1) * TQS + kr] = (int8_t)q1;
    tile[(nc + 2) * TQS + kr] = (int8_t)q2;
    tile[(nc + 3) * TQS + kr] = (int8_t)q3;
  }
  __syncthreads();
  {
    int n = t >> 2, kc = (t & 3) * 16;
    uint4 val = *(const uint4*)(tile + n * TQS + kc);
    *(uint4*)(qt + (size_t)(n0 + n) * KD + k0 + kc) = val;
  }
  for (int i = threadIdx.x; i < 256; i += blockDim.x)
    if (h[i]) atomicAdd(&hist[i], h[i]);
}

// ---------------- kth-value: parallel prefix scan over 256-bin histogram ----------------
// block 0 -> hist1, block 1 -> hist2. Replaces the serial thread-0 global scan
// (~500cy dependent loads x 510) that dominated round-1 runtime.
__global__ void finalize_kernel(const unsigned int* __restrict__ hist1,
                                const unsigned int* __restrict__ hist2,
                                float* __restrict__ out_k) {
  __shared__ unsigned int c[256];
  __shared__ int result;
  int t = threadIdx.x;
  const unsigned int* h = (blockIdx.x == 0) ? hist1 : hist2;
  c[t] = h[t];
  if (t == 0) result = 127;
  __syncthreads();
  #pragma unroll
  for (int off = 1; off < 256; off <<= 1) {
    unsigned int add = (t >= off) ? c[t - off] : 0u;
    __syncthreads();
    c[t] += add;
    __syncthreads();
  }
  // first bin whose inclusive cumsum reaches KTH
  unsigned int prev = (t == 0) ? 0u : c[t - 1];
  if (c[t] >= (unsigned int)KTH && prev < (unsigned int)KTH) result = t - 127;
  __syncthreads();
  if (t == 0) out_k[blockIdx.x] = (float)result;
}

// ---------------- i8 GEMM: C = q1[M][K] @ q2t[N][K]^T, scaled ----------------
// 128x128 tile, BK=128, 4 waves (2x2), each wave 64x64 via 4x4 of 16x16x64 i8 MFMA.
__global__ __launch_bounds__(256, 2) void gemm_i8_kernel(
    const int8_t* __restrict__ qa, const int8_t* __restrict__ qb,
    float* __restrict__ out, const unsigned int* __restrict__ sbits) {
  __shared__ __align__(16) int8_t Asm[128 * 128];
  __shared__ __align__(16) int8_t Bsm[128 * 128];

  // XCD-aware supergroup: each XCD (bid&7) owns an 8-brow stripe; within the
  // stripe walk rows-fast in 8x8 panels so the concurrent working set per XCD
  // is ~2MB A-panel + ~2MB B-panel ~= L2 size. Bijective: 4096 = 8*8*64.
  int bid = blockIdx.x;
  int xcd = bid & 7;
  int local = bid >> 3;               // 0..511
  int brow = xcd * 8 + (local & 7);   // 0..63
  int bcol = local >> 3;              // 0..63

  int t = threadIdx.x;
  int lane = t & 63;
  int w = t >> 6;
  int wr = (w >> 1) * 64, wc = (w & 1) * 64;

  v4i acc[4][4] = {};

  const int8_t* ga = qa + (size_t)brow * 128 * KD;
  const int8_t* gb = qb + (size_t)bcol * 128 * KD;

  int srow = t >> 3;     // 0..31 (row within 32-row staging slab)
  int schunk = t & 7;    // swizzled 16B-chunk slot in LDS row

  for (int kt = 0; kt < KD / 128; ++kt) {
    int kbase = kt * 128;
    #pragma unroll
    for (int i = 0; i < 4; ++i) {
      int row = i * 32 + srow;
      int gchunk = schunk ^ (row & 7);  // pre-swizzled global source
      gload_lds16(ga + (size_t)row * KD + kbase + gchunk * 16, Asm + i * 4096 + t * 16);
    }
    #pragma unroll
    for (int i = 0; i < 4; ++i) {
      int row = i * 32 + srow;
      int gchunk = schunk ^ (row & 7);
      gload_lds16(gb + (size_t)row * KD + kbase + gchunk * 16, Bsm + i * 4096 + t * 16);
    }
    __syncthreads();
    #pragma unroll
    for (int kh = 0; kh < 2; ++kh) {
      v4i aF[4], bF[4];
      #pragma unroll
      for (int m = 0; m < 4; ++m) {
        int row = wr + m * 16 + (lane & 15);
        int chunk = (kh * 4 + (lane >> 4)) ^ (row & 7);
        aF[m] = *(const v4i*)(Asm + row * 128 + chunk * 16);
      }
      #pragma unroll
      for (int n = 0; n < 4; ++n) {
        int row = wc + n * 16 + (lane & 15);
        int chunk = (kh * 4 + (lane >> 4)) ^ (row & 7);
        bF[n] = *(const v4i*)(Bsm + row * 128 + chunk * 16);
      }
      #pragma unroll
      for (int m = 0; m < 4; ++m)
        #pragma unroll
        for (int n = 0; n < 4; ++n)
          acc[m][n] = __builtin_amdgcn_mfma_i32_16x16x64_i8(aF[m], bF[n], acc[m][n], 0, 0, 0);
    }
    __syncthreads();
  }

  float s1 = __uint_as_float(sbits[0]);
  float s2 = __uint_as_float(sbits[1]);
  float scale = s1 * s2 / (127.0f * 127.0f);
  int orow = brow * 128 + wr + ((lane >> 4) * 4);
  int ocol = bcol * 128 + wc + (lane & 15);
  #pragma unroll
  for (int m = 0; m < 4; ++m)
    #pragma unroll
    for (int n = 0; n < 4; ++n)
      #pragma unroll
      for (int r = 0; r < 4; ++r)
        out[(size_t)(orow + m * 16 + r) * ND + (ocol + n * 16)] = (float)acc[m][n][r] * scale;
}

extern "C" void kernel_launch(void* const* d_in, const int* in_sizes, int n_in,
                              void* d_out, int out_size, void* d_ws, size_t ws_size,
                              hipStream_t stream) {
  const float* x1 = (const float*)d_in[0];
  const float* x2 = (const float*)d_in[1];
  float* out = (float*)d_out;
  uint8_t* ws = (uint8_t*)d_ws;

  unsigned int* sbits = (unsigned int*)ws;                 // [0]=s1 bits, [1]=s2 bits
  unsigned int* hist1 = (unsigned int*)(ws + 256);
  unsigned int* hist2 = (unsigned int*)(ws + 256 + 1024);
  int8_t* q1  = (int8_t*)(ws + 4096);
  int8_t* q2t = q1 + (size_t)MD * KD;

  const int n4_1 = MD * KD / 4;  // 4,194,304 float4s
  const int n4_2 = KD * ND / 4;

  hipMemsetAsync(ws, 0, 4096, stream);
  absmax_kernel<<<2048, 256, 0, stream>>>(x1, n4_1, sbits + 0);
  absmax_kernel<<<2048, 256, 0, stream>>>(x2, n4_2, sbits + 1);
  quant_hist_kernel<<<2048, 256, 0, stream>>>(x1, q1, n4_1, sbits + 0, hist1);
  transq_kernel<<<dim3(ND / 64, KD / 64), 256, 0, stream>>>(x2, q2t, sbits + 1, hist2);
  finalize_kernel<<<2, 256, 0, stream>>>(hist1, hist2, out + (size_t)MD * ND);
  gemm_i8_kernel<<<4096, 256, 0, stream>>>(q1, q2t, out, sbits);
}

// Round 3
// 466.893 us; speedup vs baseline: 1.1883x; 1.0364x over previous
//
#include <hip/hip_runtime.h>
#include <stdint.h>

#define MD 8192
#define ND 8192
#define KD 2048
#define KTH 15099494  // int(8192*2048*0.9)

#define NCOPY 16   // privatized LDS histogram copies
#define HSTR 257   // copy stride in words; 257 % 32 == 1 -> copies land in distinct banks

typedef int v4i __attribute__((ext_vector_type(4)));

__device__ __forceinline__ void gload_lds16(const void* g, void* l) {
  __builtin_amdgcn_global_load_lds(
      (const __attribute__((address_space(1))) uint32_t*)g,
      (__attribute__((address_space(3))) uint32_t*)l, 16, 0, 0);
}

// ---------------- absmax reduction ----------------
__global__ void absmax_kernel(const float* __restrict__ x, int n4, unsigned int* out) {
  int tid = blockIdx.x * blockDim.x + threadIdx.x;
  int stride = gridDim.x * blockDim.x;
  const float4* p = (const float4*)x;
  float m = 0.f;
  for (int i = tid; i < n4; i += stride) {
    float4 v = p[i];
    m = fmaxf(m, fmaxf(fmaxf(fabsf(v.x), fabsf(v.y)), fmaxf(fabsf(v.z), fabsf(v.w))));
  }
  #pragma unroll
  for (int off = 32; off; off >>= 1) m = fmaxf(m, __shfl_down(m, off, 64));
  if ((threadIdx.x & 63) == 0) atomicMax(out, __float_as_uint(m));
}

// ---------------- quantize x1 (row-major keep) + privatized histogram ----------------
__global__ void quant_hist_kernel(const float* __restrict__ x, int8_t* __restrict__ q,
                                  int n4, const unsigned int* sbits, unsigned int* hist) {
  __shared__ unsigned int h[NCOPY * HSTR];
  for (int i = threadIdx.x; i < NCOPY * HSTR; i += blockDim.x) h[i] = 0;
  __syncthreads();
  unsigned int* hc = h + (threadIdx.x & (NCOPY - 1)) * HSTR;
  float s = __uint_as_float(*sbits);
  int tid = blockIdx.x * blockDim.x + threadIdx.x;
  int stride = gridDim.x * blockDim.x;
  const float4* p = (const float4*)x;
  uint32_t* qo = (uint32_t*)q;
  for (int i = tid; i < n4; i += stride) {
    float4 v = p[i];
    int q0 = (int)rintf(v.x / s * 127.0f);   // keep (x/s)*127 order: matches np bit-exactly
    int q1 = (int)rintf(v.y / s * 127.0f);
    int q2 = (int)rintf(v.z / s * 127.0f);
    int q3 = (int)rintf(v.w / s * 127.0f);
    atomicAdd(&hc[q0 + 127], 1u);
    atomicAdd(&hc[q1 + 127], 1u);
    atomicAdd(&hc[q2 + 127], 1u);
    atomicAdd(&hc[q3 + 127], 1u);
    uint32_t packed = (uint32_t)(uint8_t)(int8_t)q0 |
                      ((uint32_t)(uint8_t)(int8_t)q1 << 8) |
                      ((uint32_t)(uint8_t)(int8_t)q2 << 16) |
                      ((uint32_t)(uint8_t)(int8_t)q3 << 24);
    qo[i] = packed;
  }
  __syncthreads();
  {
    int b = threadIdx.x;  // blockDim == 256, one bin per thread
    unsigned int sum = 0;
    #pragma unroll
    for (int c = 0; c < NCOPY; ++c) sum += h[c * HSTR + b];
    if (sum) atomicAdd(&hist[b], sum);
  }
}

// ---------------- quantize x2 transposed ([K][N] -> q2t[N][K]) + privatized histogram ----
// 64x64 tile per block, 4x4 micro-tile per thread: 4 coalesced float4 loads,
// pack k-quads into u32s, 4x ds_write_b32 (stride-17 rows, <=2-way banks),
// reassemble via 4x ds_read_b32 -> one global_store_dwordx4.
#define TSTR 17  // LDS tile row stride in words
__global__ void transq_kernel(const float* __restrict__ x, int8_t* __restrict__ qt,
                              const unsigned int* sbits, unsigned int* hist) {
  __shared__ unsigned int tile2[64 * TSTR];
  __shared__ unsigned int h[NCOPY * HSTR];
  for (int i = threadIdx.x; i < NCOPY * HSTR; i += blockDim.x) h[i] = 0;
  __syncthreads();
  unsigned int* hc = h + (threadIdx.x & (NCOPY - 1)) * HSTR;
  float s = __uint_as_float(*sbits);
  int n0 = blockIdx.x * 64, k0 = blockIdx.y * 64;
  int t = threadIdx.x;
  int nq = t & 15, kq = t >> 4;  // n-quad, k-quad within the 64x64 tile
  unsigned int pk[4] = {0, 0, 0, 0};
  #pragma unroll
  for (int j = 0; j < 4; ++j) {
    float4 v = *(const float4*)(x + (size_t)(k0 + kq * 4 + j) * ND + n0 + nq * 4);
    int q0 = (int)rintf(v.x / s * 127.0f);
    int q1 = (int)rintf(v.y / s * 127.0f);
    int q2 = (int)rintf(v.z / s * 127.0f);
    int q3 = (int)rintf(v.w / s * 127.0f);
    atomicAdd(&hc[q0 + 127], 1u);
    atomicAdd(&hc[q1 + 127], 1u);
    atomicAdd(&hc[q2 + 127], 1u);
    atomicAdd(&hc[q3 + 127], 1u);
    pk[0] |= ((unsigned int)(uint8_t)(int8_t)q0) << (8 * j);
    pk[1] |= ((unsigned int)(uint8_t)(int8_t)q1) << (8 * j);
    pk[2] |= ((unsigned int)(uint8_t)(int8_t)q2) << (8 * j);
    pk[3] |= ((unsigned int)(uint8_t)(int8_t)q3) << (8 * j);
  }
  #pragma unroll
  for (int i = 0; i < 4; ++i) tile2[(nq * 4 + i) * TSTR + kq] = pk[i];
  __syncthreads();
  {
    int n = t >> 2, c = t & 3;  // row within tile, 16B chunk within row
    uint4 val;
    val.x = tile2[n * TSTR + c * 4 + 0];
    val.y = tile2[n * TSTR + c * 4 + 1];
    val.z = tile2[n * TSTR + c * 4 + 2];
    val.w = tile2[n * TSTR + c * 4 + 3];
    *(uint4*)(qt + (size_t)(n0 + n) * KD + k0 + c * 16) = val;
  }
  __syncthreads();
  {
    int b = threadIdx.x;
    unsigned int sum = 0;
    #pragma unroll
    for (int c = 0; c < NCOPY; ++c) sum += h[c * HSTR + b];
    if (sum) atomicAdd(&hist[b], sum);
  }
}

// ---------------- kth-value: parallel prefix scan over 256-bin histogram ----------------
__global__ void finalize_kernel(const unsigned int* __restrict__ hist1,
                                const unsigned int* __restrict__ hist2,
                                float* __restrict__ out_k) {
  __shared__ unsigned int c[256];
  __shared__ int result;
  int t = threadIdx.x;
  const unsigned int* h = (blockIdx.x == 0) ? hist1 : hist2;
  c[t] = h[t];
  if (t == 0) result = 127;
  __syncthreads();
  #pragma unroll
  for (int off = 1; off < 256; off <<= 1) {
    unsigned int add = (t >= off) ? c[t - off] : 0u;
    __syncthreads();
    c[t] += add;
    __syncthreads();
  }
  unsigned int prev = (t == 0) ? 0u : c[t - 1];
  if (c[t] >= (unsigned int)KTH && prev < (unsigned int)KTH) result = t - 127;
  __syncthreads();
  if (t == 0) out_k[blockIdx.x] = (float)result;
}

// ---------------- i8 GEMM: C = q1[M][K] @ q2t[N][K]^T, scaled (unchanged) ----------------
__global__ __launch_bounds__(256, 2) void gemm_i8_kernel(
    const int8_t* __restrict__ qa, const int8_t* __restrict__ qb,
    float* __restrict__ out, const unsigned int* __restrict__ sbits) {
  __shared__ __align__(16) int8_t Asm[128 * 128];
  __shared__ __align__(16) int8_t Bsm[128 * 128];

  int bid = blockIdx.x;
  int xcd = bid & 7;
  int local = bid >> 3;               // 0..511
  int brow = xcd * 8 + (local & 7);   // 0..63
  int bcol = local >> 3;              // 0..63

  int t = threadIdx.x;
  int lane = t & 63;
  int w = t >> 6;
  int wr = (w >> 1) * 64, wc = (w & 1) * 64;

  v4i acc[4][4] = {};

  const int8_t* ga = qa + (size_t)brow * 128 * KD;
  const int8_t* gb = qb + (size_t)bcol * 128 * KD;

  int srow = t >> 3;
  int schunk = t & 7;

  for (int kt = 0; kt < KD / 128; ++kt) {
    int kbase = kt * 128;
    #pragma unroll
    for (int i = 0; i < 4; ++i) {
      int row = i * 32 + srow;
      int gchunk = schunk ^ (row & 7);
      gload_lds16(ga + (size_t)row * KD + kbase + gchunk * 16, Asm + i * 4096 + t * 16);
    }
    #pragma unroll
    for (int i = 0; i < 4; ++i) {
      int row = i * 32 + srow;
      int gchunk = schunk ^ (row & 7);
      gload_lds16(gb + (size_t)row * KD + kbase + gchunk * 16, Bsm + i * 4096 + t * 16);
    }
    __syncthreads();
    #pragma unroll
    for (int kh = 0; kh < 2; ++kh) {
      v4i aF[4], bF[4];
      #pragma unroll
      for (int m = 0; m < 4; ++m) {
        int row = wr + m * 16 + (lane & 15);
        int chunk = (kh * 4 + (lane >> 4)) ^ (row & 7);
        aF[m] = *(const v4i*)(Asm + row * 128 + chunk * 16);
      }
      #pragma unroll
      for (int n = 0; n < 4; ++n) {
        int row = wc + n * 16 + (lane & 15);
        int chunk = (kh * 4 + (lane >> 4)) ^ (row & 7);
        bF[n] = *(const v4i*)(Bsm + row * 128 + chunk * 16);
      }
      #pragma unroll
      for (int m = 0; m < 4; ++m)
        #pragma unroll
        for (int n = 0; n < 4; ++n)
          acc[m][n] = __builtin_amdgcn_mfma_i32_16x16x64_i8(aF[m], bF[n], acc[m][n], 0, 0, 0);
    }
    __syncthreads();
  }

  float s1 = __uint_as_float(sbits[0]);
  float s2 = __uint_as_float(sbits[1]);
  float scale = s1 * s2 / (127.0f * 127.0f);
  int orow = brow * 128 + wr + ((lane >> 4) * 4);
  int ocol = bcol * 128 + wc + (lane & 15);
  #pragma unroll
  for (int m = 0; m < 4; ++m)
    #pragma unroll
    for (int n = 0; n < 4; ++n)
      #pragma unroll
      for (int r = 0; r < 4; ++r)
        out[(size_t)(orow + m * 16 + r) * ND + (ocol + n * 16)] = (float)acc[m][n][r] * scale;
}

extern "C" void kernel_launch(void* const* d_in, const int* in_sizes, int n_in,
                              void* d_out, int out_size, void* d_ws, size_t ws_size,
                              hipStream_t stream) {
  const float* x1 = (const float*)d_in[0];
  const float* x2 = (const float*)d_in[1];
  float* out = (float*)d_out;
  uint8_t* ws = (uint8_t*)d_ws;

  unsigned int* sbits = (unsigned int*)ws;
  unsigned int* hist1 = (unsigned int*)(ws + 256);
  unsigned int* hist2 = (unsigned int*)(ws + 256 + 1024);
  int8_t* q1  = (int8_t*)(ws + 4096);
  int8_t* q2t = q1 + (size_t)MD * KD;

  const int n4_1 = MD * KD / 4;
  const int n4_2 = KD * ND / 4;

  hipMemsetAsync(ws, 0, 4096, stream);
  absmax_kernel<<<2048, 256, 0, stream>>>(x1, n4_1, sbits + 0);
  absmax_kernel<<<2048, 256, 0, stream>>>(x2, n4_2, sbits + 1);
  quant_hist_kernel<<<1024, 256, 0, stream>>>(x1, q1, n4_1, sbits + 0, hist1);
  transq_kernel<<<dim3(ND / 64, KD / 64), 256, 0, stream>>>(x2, q2t, sbits + 1, hist2);
  finalize_kernel<<<2, 256, 0, stream>>>(hist1, hist2, out + (size_t)MD * ND);
  gemm_i8_kernel<<<4096, 256, 0, stream>>>(q1, q2t, out, sbits);
}

// Round 4
// 248.720 us; speedup vs baseline: 2.2307x; 1.8772x over previous
//
#include <hip/hip_runtime.h>
#include <stdint.h>

#define MD 8192
#define ND 8192
#define KD 2048
#define KTH 15099494  // int(8192*2048*0.9)

#define NCOPY 16   // privatized LDS histogram copies
#define HSTR 257   // copy stride in words; 257 % 32 == 1 -> distinct banks per copy
#define NPART 8    // global histogram partials (cuts per-address atomic chains 8x)

typedef int v4i __attribute__((ext_vector_type(4)));

__device__ __forceinline__ void gload_lds16(const void* g, void* l) {
  __builtin_amdgcn_global_load_lds(
      (const __attribute__((address_space(1))) uint32_t*)g,
      (__attribute__((address_space(3))) uint32_t*)l, 16, 0, 0);
}

// ---------------- absmax: both tensors, ONE global atomic per block ----------------
__global__ void absmax2_kernel(const float* __restrict__ x1, const float* __restrict__ x2,
                               unsigned int* sbits) {
  __shared__ float wred[4];
  const float4* p = (const float4*)(blockIdx.y ? x2 : x1);
  const int n4 = MD * KD / 4;
  int tid = blockIdx.x * blockDim.x + threadIdx.x;
  int stride = gridDim.x * blockDim.x;
  float m = 0.f;
  for (int i = tid; i < n4; i += stride) {
    float4 v = p[i];
    m = fmaxf(m, fmaxf(fmaxf(fabsf(v.x), fabsf(v.y)), fmaxf(fabsf(v.z), fabsf(v.w))));
  }
  #pragma unroll
  for (int off = 32; off; off >>= 1) m = fmaxf(m, __shfl_down(m, off, 64));
  if ((threadIdx.x & 63) == 0) wred[threadIdx.x >> 6] = m;
  __syncthreads();
  if (threadIdx.x == 0) {
    float bm = fmaxf(fmaxf(wred[0], wred[1]), fmaxf(wred[2], wred[3]));
    atomicMax(&sbits[blockIdx.y], __float_as_uint(bm));  // 512 atomics/address total
  }
}

// ---------------- quantize x1 (row-major keep) + privatized histogram ----------------
__global__ void quant_hist_kernel(const float* __restrict__ x, int8_t* __restrict__ q,
                                  int n4, const unsigned int* sbits, unsigned int* hist) {
  __shared__ unsigned int h[NCOPY * HSTR];
  for (int i = threadIdx.x; i < NCOPY * HSTR; i += blockDim.x) h[i] = 0;
  __syncthreads();
  unsigned int* hc = h + (threadIdx.x & (NCOPY - 1)) * HSTR;
  float s = __uint_as_float(*sbits);
  int tid = blockIdx.x * blockDim.x + threadIdx.x;
  int stride = gridDim.x * blockDim.x;
  const float4* p = (const float4*)x;
  uint32_t* qo = (uint32_t*)q;
  for (int i = tid; i < n4; i += stride) {
    float4 v = p[i];
    int q0 = (int)rintf(v.x / s * 127.0f);   // keep (x/s)*127 order: matches np bit-exactly
    int q1 = (int)rintf(v.y / s * 127.0f);
    int q2 = (int)rintf(v.z / s * 127.0f);
    int q3 = (int)rintf(v.w / s * 127.0f);
    atomicAdd(&hc[q0 + 127], 1u);
    atomicAdd(&hc[q1 + 127], 1u);
    atomicAdd(&hc[q2 + 127], 1u);
    atomicAdd(&hc[q3 + 127], 1u);
    uint32_t packed = (uint32_t)(uint8_t)(int8_t)q0 |
                      ((uint32_t)(uint8_t)(int8_t)q1 << 8) |
                      ((uint32_t)(uint8_t)(int8_t)q2 << 16) |
                      ((uint32_t)(uint8_t)(int8_t)q3 << 24);
    qo[i] = packed;
  }
  __syncthreads();
  {
    int b = threadIdx.x;  // blockDim == 256
    unsigned int sum = 0;
    #pragma unroll
    for (int c = 0; c < NCOPY; ++c) sum += h[c * HSTR + b];
    if (sum) atomicAdd(&hist[(blockIdx.x & (NPART - 1)) * 256 + b], sum);
  }
}

// ---------------- quantize x2 transposed ([K][N] -> q2t[N][K]) + privatized histogram ----
#define TSTR 17  // LDS tile row stride in words
__global__ void transq_kernel(const float* __restrict__ x, int8_t* __restrict__ qt,
                              const unsigned int* sbits, unsigned int* hist) {
  __shared__ unsigned int tile2[64 * TSTR];
  __shared__ unsigned int h[NCOPY * HSTR];
  for (int i = threadIdx.x; i < NCOPY * HSTR; i += blockDim.x) h[i] = 0;
  __syncthreads();
  unsigned int* hc = h + (threadIdx.x & (NCOPY - 1)) * HSTR;
  float s = __uint_as_float(*sbits);
  int n0 = blockIdx.x * 64, k0 = blockIdx.y * 64;
  int t = threadIdx.x;
  int nq = t & 15, kq = t >> 4;
  unsigned int pk[4] = {0, 0, 0, 0};
  #pragma unroll
  for (int j = 0; j < 4; ++j) {
    float4 v = *(const float4*)(x + (size_t)(k0 + kq * 4 + j) * ND + n0 + nq * 4);
    int q0 = (int)rintf(v.x / s * 127.0f);
    int q1 = (int)rintf(v.y / s * 127.0f);
    int q2 = (int)rintf(v.z / s * 127.0f);
    int q3 = (int)rintf(v.w / s * 127.0f);
    atomicAdd(&hc[q0 + 127], 1u);
    atomicAdd(&hc[q1 + 127], 1u);
    atomicAdd(&hc[q2 + 127], 1u);
    atomicAdd(&hc[q3 + 127], 1u);
    pk[0] |= ((unsigned int)(uint8_t)(int8_t)q0) << (8 * j);
    pk[1] |= ((unsigned int)(uint8_t)(int8_t)q1) << (8 * j);
    pk[2] |= ((unsigned int)(uint8_t)(int8_t)q2) << (8 * j);
    pk[3] |= ((unsigned int)(uint8_t)(int8_t)q3) << (8 * j);
  }
  #pragma unroll
  for (int i = 0; i < 4; ++i) tile2[(nq * 4 + i) * TSTR + kq] = pk[i];
  __syncthreads();
  {
    int n = t >> 2, c = t & 3;
    uint4 val;
    val.x = tile2[n * TSTR + c * 4 + 0];
    val.y = tile2[n * TSTR + c * 4 + 1];
    val.z = tile2[n * TSTR + c * 4 + 2];
    val.w = tile2[n * TSTR + c * 4 + 3];
    *(uint4*)(qt + (size_t)(n0 + n) * KD + k0 + c * 16) = val;
  }
  __syncthreads();
  {
    int b = threadIdx.x;
    unsigned int sum = 0;
    #pragma unroll
    for (int c = 0; c < NCOPY; ++c) sum += h[c * HSTR + b];
    if (sum) atomicAdd(&hist[((blockIdx.x + blockIdx.y) & (NPART - 1)) * 256 + b], sum);
  }
}

// ---------------- kth-value: sum partials, prefix scan, pick crossing ----------------
__global__ void finalize_kernel(const unsigned int* __restrict__ hist1,
                                const unsigned int* __restrict__ hist2,
                                float* __restrict__ out_k) {
  __shared__ unsigned int c[256];
  __shared__ int result;
  int t = threadIdx.x;
  const unsigned int* h = (blockIdx.x == 0) ? hist1 : hist2;
  unsigned int sum = 0;
  #pragma unroll
  for (int p = 0; p < NPART; ++p) sum += h[p * 256 + t];
  c[t] = sum;
  if (t == 0) result = 127;
  __syncthreads();
  #pragma unroll
  for (int off = 1; off < 256; off <<= 1) {
    unsigned int add = (t >= off) ? c[t - off] : 0u;
    __syncthreads();
    c[t] += add;
    __syncthreads();
  }
  unsigned int prev = (t == 0) ? 0u : c[t - 1];
  if (c[t] >= (unsigned int)KTH && prev < (unsigned int)KTH) result = t - 127;
  __syncthreads();
  if (t == 0) out_k[blockIdx.x] = (float)result;
}

// ---------------- i8 GEMM, 2-phase prefetch (T3-minimum), BK=64 double-buffered ------
// 128x128 tile, 4 waves (2x2), per wave 4x4 of 16x16x64 i8 MFMA per K-tile.
// LDS: 2 x (8KB A + 8KB B) = 32 KB. One __syncthreads per K-tile (implicit
// vmcnt(0) drains the in-flight STAGE). Swizzle: chunk ^= (row>>1)&3 on BOTH
// the staging global-source and the ds_read side (same involution).
__global__ __launch_bounds__(256, 3) void gemm_i8_kernel(
    const int8_t* __restrict__ qa, const int8_t* __restrict__ qb,
    float* __restrict__ out, const unsigned int* __restrict__ sbits) {
  __shared__ __align__(16) int8_t Asm[2][128 * 64];
  __shared__ __align__(16) int8_t Bsm[2][128 * 64];

  // XCD supergroup (bijective, 4096 = 8*8*64): ~4MB working set per XCD ~= L2
  int bid = blockIdx.x;
  int xcd = bid & 7;
  int local = bid >> 3;
  int brow = xcd * 8 + (local & 7);
  int bcol = local >> 3;

  int t = threadIdx.x;
  int lane = t & 63;
  int w = t >> 6;
  int wr = (w >> 1) * 64, wc = (w & 1) * 64;

  v4i acc[4][4] = {};

  const int8_t* ga = qa + (size_t)brow * 128 * KD;
  const int8_t* gb = qb + (size_t)bcol * 128 * KD;

  int srow = t >> 2;   // 0..63: row within 64-row staging pass
  int schunk = t & 3;  // 16B chunk slot within 64B row

  auto STAGE = [&](int kt, int buf) {
    int kbase = kt * 64;
    #pragma unroll
    for (int i = 0; i < 2; ++i) {
      int row = i * 64 + srow;
      int gchunk = schunk ^ ((row >> 1) & 3);
      gload_lds16(ga + (size_t)row * KD + kbase + gchunk * 16, Asm[buf] + i * 4096 + t * 16);
    }
    #pragma unroll
    for (int i = 0; i < 2; ++i) {
      int row = i * 64 + srow;
      int gchunk = schunk ^ ((row >> 1) & 3);
      gload_lds16(gb + (size_t)row * KD + kbase + gchunk * 16, Bsm[buf] + i * 4096 + t * 16);
    }
  };

  auto COMPUTE = [&](int buf) {
    v4i aF[4], bF[4];
    #pragma unroll
    for (int m = 0; m < 4; ++m) {
      int row = wr + m * 16 + (lane & 15);
      int chunk = (lane >> 4) ^ ((row >> 1) & 3);
      aF[m] = *(const v4i*)(Asm[buf] + row * 64 + chunk * 16);
    }
    #pragma unroll
    for (int n = 0; n < 4; ++n) {
      int row = wc + n * 16 + (lane & 15);
      int chunk = (lane >> 4) ^ ((row >> 1) & 3);
      bF[n] = *(const v4i*)(Bsm[buf] + row * 64 + chunk * 16);
    }
    #pragma unroll
    for (int m = 0; m < 4; ++m)
      #pragma unroll
      for (int n = 0; n < 4; ++n)
        acc[m][n] = __builtin_amdgcn_mfma_i32_16x16x64_i8(aF[m], bF[n], acc[m][n], 0, 0, 0);
  };

  STAGE(0, 0);
  __syncthreads();
  for (int kt = 0; kt < KD / 64; kt += 2) {
    STAGE(kt + 1, 1);                       // in flight across COMPUTE(0)
    COMPUTE(0);
    __syncthreads();                        // drains vmcnt -> buf1 ready
    if (kt + 2 < KD / 64) STAGE(kt + 2, 0); // in flight across COMPUTE(1)
    COMPUTE(1);
    __syncthreads();                        // drains vmcnt -> buf0 ready
  }

  float s1 = __uint_as_float(sbits[0]);
  float s2 = __uint_as_float(sbits[1]);
  float scale = s1 * s2 / (127.0f * 127.0f);
  int orow = brow * 128 + wr + ((lane >> 4) * 4);
  int ocol = bcol * 128 + wc + (lane & 15);
  #pragma unroll
  for (int m = 0; m < 4; ++m)
    #pragma unroll
    for (int n = 0; n < 4; ++n)
      #pragma unroll
      for (int r = 0; r < 4; ++r)
        out[(size_t)(orow + m * 16 + r) * ND + (ocol + n * 16)] = (float)acc[m][n][r] * scale;
}

extern "C" void kernel_launch(void* const* d_in, const int* in_sizes, int n_in,
                              void* d_out, int out_size, void* d_ws, size_t ws_size,
                              hipStream_t stream) {
  const float* x1 = (const float*)d_in[0];
  const float* x2 = (const float*)d_in[1];
  float* out = (float*)d_out;
  uint8_t* ws = (uint8_t*)d_ws;

  unsigned int* sbits = (unsigned int*)ws;                      // 2 words
  unsigned int* hist1 = (unsigned int*)(ws + 256);              // NPART*256 words
  unsigned int* hist2 = (unsigned int*)(ws + 256 + 8192);      // NPART*256 words
  int8_t* q1  = (int8_t*)(ws + 32768);
  int8_t* q2t = q1 + (size_t)MD * KD;

  const int n4_1 = MD * KD / 4;
  const int n4_2 = KD * ND / 4;

  hipMemsetAsync(ws, 0, 32768, stream);
  absmax2_kernel<<<dim3(512, 2), 256, 0, stream>>>(x1, x2, sbits);
  quant_hist_kernel<<<1024, 256, 0, stream>>>(x1, q1, n4_1, sbits + 0, hist1);
  transq_kernel<<<dim3(ND / 64, KD / 64), 256, 0, stream>>>(x2, q2t, sbits + 1, hist2);
  finalize_kernel<<<2, 256, 0, stream>>>(hist1, hist2, out + (size_t)MD * ND);
  gemm_i8_kernel<<<4096, 256, 0, stream>>>(q1, q2t, out, sbits);
}

// Round 5
// 232.637 us; speedup vs baseline: 2.3849x; 1.0691x over previous
//
#include <hip/hip_runtime.h>
#include <stdint.h>

#define MD 8192
#define ND 8192
#define KD 2048
#define KTH 15099494  // int(8192*2048*0.9)

#define NCOPY 16   // privatized LDS histogram copies
#define HSTR 257   // copy stride in words; 257 % 32 == 1 -> distinct banks per copy
#define NPART 8    // global histogram partials

typedef int v4i __attribute__((ext_vector_type(4)));

__device__ __forceinline__ void gload_lds16(const void* g, void* l) {
  __builtin_amdgcn_global_load_lds(
      (const __attribute__((address_space(1))) uint32_t*)g,
      (__attribute__((address_space(3))) uint32_t*)l, 16, 0, 0);
}

// ---------------- absmax: both tensors, ONE global atomic per block ----------------
__global__ void absmax2_kernel(const float* __restrict__ x1, const float* __restrict__ x2,
                               unsigned int* sbits) {
  __shared__ float wred[4];
  const float4* p = (const float4*)(blockIdx.y ? x2 : x1);
  const int n4 = MD * KD / 4;
  int tid = blockIdx.x * blockDim.x + threadIdx.x;
  int stride = gridDim.x * blockDim.x;
  float m = 0.f;
  for (int i = tid; i < n4; i += stride) {
    float4 v = p[i];
    m = fmaxf(m, fmaxf(fmaxf(fabsf(v.x), fabsf(v.y)), fmaxf(fabsf(v.z), fabsf(v.w))));
  }
  #pragma unroll
  for (int off = 32; off; off >>= 1) m = fmaxf(m, __shfl_down(m, off, 64));
  if ((threadIdx.x & 63) == 0) wred[threadIdx.x >> 6] = m;
  __syncthreads();
  if (threadIdx.x == 0) {
    float bm = fmaxf(fmaxf(wred[0], wred[1]), fmaxf(wred[2], wred[3]));
    atomicMax(&sbits[blockIdx.y], __float_as_uint(bm));
  }
}

// ---------------- quantize x1 (row-major keep) + privatized histogram ----------------
__global__ void quant_hist_kernel(const float* __restrict__ x, int8_t* __restrict__ q,
                                  int n4, const unsigned int* sbits, unsigned int* hist) {
  __shared__ unsigned int h[NCOPY * HSTR];
  for (int i = threadIdx.x; i < NCOPY * HSTR; i += blockDim.x) h[i] = 0;
  __syncthreads();
  unsigned int* hc = h + (threadIdx.x & (NCOPY - 1)) * HSTR;
  float s = __uint_as_float(*sbits);
  int tid = blockIdx.x * blockDim.x + threadIdx.x;
  int stride = gridDim.x * blockDim.x;
  const float4* p = (const float4*)x;
  uint32_t* qo = (uint32_t*)q;
  for (int i = tid; i < n4; i += stride) {
    float4 v = p[i];
    int q0 = (int)rintf(v.x / s * 127.0f);   // keep (x/s)*127 order: matches np bit-exactly
    int q1 = (int)rintf(v.y / s * 127.0f);
    int q2 = (int)rintf(v.z / s * 127.0f);
    int q3 = (int)rintf(v.w / s * 127.0f);
    atomicAdd(&hc[q0 + 127], 1u);
    atomicAdd(&hc[q1 + 127], 1u);
    atomicAdd(&hc[q2 + 127], 1u);
    atomicAdd(&hc[q3 + 127], 1u);
    uint32_t packed = (uint32_t)(uint8_t)(int8_t)q0 |
                      ((uint32_t)(uint8_t)(int8_t)q1 << 8) |
                      ((uint32_t)(uint8_t)(int8_t)q2 << 16) |
                      ((uint32_t)(uint8_t)(int8_t)q3 << 24);
    qo[i] = packed;
  }
  __syncthreads();
  {
    int b = threadIdx.x;
    unsigned int sum = 0;
    #pragma unroll
    for (int c = 0; c < NCOPY; ++c) sum += h[c * HSTR + b];
    if (sum) atomicAdd(&hist[(blockIdx.x & (NPART - 1)) * 256 + b], sum);
  }
}

// ---------------- quantize x2 transposed ([K][N] -> q2t[N][K]) + privatized histogram ----
#define TSTR 17
__global__ void transq_kernel(const float* __restrict__ x, int8_t* __restrict__ qt,
                              const unsigned int* sbits, unsigned int* hist) {
  __shared__ unsigned int tile2[64 * TSTR];
  __shared__ unsigned int h[NCOPY * HSTR];
  for (int i = threadIdx.x; i < NCOPY * HSTR; i += blockDim.x) h[i] = 0;
  __syncthreads();
  unsigned int* hc = h + (threadIdx.x & (NCOPY - 1)) * HSTR;
  float s = __uint_as_float(*sbits);
  int n0 = blockIdx.x * 64, k0 = blockIdx.y * 64;
  int t = threadIdx.x;
  int nq = t & 15, kq = t >> 4;
  unsigned int pk[4] = {0, 0, 0, 0};
  #pragma unroll
  for (int j = 0; j < 4; ++j) {
    float4 v = *(const float4*)(x + (size_t)(k0 + kq * 4 + j) * ND + n0 + nq * 4);
    int q0 = (int)rintf(v.x / s * 127.0f);
    int q1 = (int)rintf(v.y / s * 127.0f);
    int q2 = (int)rintf(v.z / s * 127.0f);
    int q3 = (int)rintf(v.w / s * 127.0f);
    atomicAdd(&hc[q0 + 127], 1u);
    atomicAdd(&hc[q1 + 127], 1u);
    atomicAdd(&hc[q2 + 127], 1u);
    atomicAdd(&hc[q3 + 127], 1u);
    pk[0] |= ((unsigned int)(uint8_t)(int8_t)q0) << (8 * j);
    pk[1] |= ((unsigned int)(uint8_t)(int8_t)q1) << (8 * j);
    pk[2] |= ((unsigned int)(uint8_t)(int8_t)q2) << (8 * j);
    pk[3] |= ((unsigned int)(uint8_t)(int8_t)q3) << (8 * j);
  }
  #pragma unroll
  for (int i = 0; i < 4; ++i) tile2[(nq * 4 + i) * TSTR + kq] = pk[i];
  __syncthreads();
  {
    int n = t >> 2, c = t & 3;
    uint4 val;
    val.x = tile2[n * TSTR + c * 4 + 0];
    val.y = tile2[n * TSTR + c * 4 + 1];
    val.z = tile2[n * TSTR + c * 4 + 2];
    val.w = tile2[n * TSTR + c * 4 + 3];
    *(uint4*)(qt + (size_t)(n0 + n) * KD + k0 + c * 16) = val;
  }
  __syncthreads();
  {
    int b = threadIdx.x;
    unsigned int sum = 0;
    #pragma unroll
    for (int c = 0; c < NCOPY; ++c) sum += h[c * HSTR + b];
    if (sum) atomicAdd(&hist[((blockIdx.x + blockIdx.y) & (NPART - 1)) * 256 + b], sum);
  }
}

// ---------------- kth-value: sum partials, prefix scan, pick crossing ----------------
__global__ void finalize_kernel(const unsigned int* __restrict__ hist1,
                                const unsigned int* __restrict__ hist2,
                                float* __restrict__ out_k) {
  __shared__ unsigned int c[256];
  __shared__ int result;
  int t = threadIdx.x;
  const unsigned int* h = (blockIdx.x == 0) ? hist1 : hist2;
  unsigned int sum = 0;
  #pragma unroll
  for (int p = 0; p < NPART; ++p) sum += h[p * 256 + t];
  c[t] = sum;
  if (t == 0) result = 127;
  __syncthreads();
  #pragma unroll
  for (int off = 1; off < 256; off <<= 1) {
    unsigned int add = (t >= off) ? c[t - off] : 0u;
    __syncthreads();
    c[t] += add;
    __syncthreads();
  }
  unsigned int prev = (t == 0) ? 0u : c[t - 1];
  if (c[t] >= (unsigned int)KTH && prev < (unsigned int)KTH) result = t - 127;
  __syncthreads();
  if (t == 0) out_k[blockIdx.x] = (float)result;
}

// ---------------- i8 GEMM: counted-vmcnt deep pipeline (T3+T4+T5) -----------------
// 256x256 tile, 512 thr (8 waves 2Mx4N), per-wave 128x64 out = 8x4 frags.
// K split into 32 phases of 64 cols. LDS: 4 k-chunk regions per matrix
// (region = phase&3), 16KB each -> 128KB dynamic. Phase h:
//   STAGE(h+2) -> s_waitcnt vmcnt(8) [units h+1,h+2 stay in flight; NEVER 0]
//   -> raw s_barrier -> 12 ds_read_b128 -> setprio(1) 32 MFMA setprio(0).
// NO __syncthreads in the loop (its implicit vmcnt(0) is the 2-phase ceiling).
// Race audit: STAGE(h+2) targets region (h-2)&3, last read in phase h-2;
// all waves passed barrier(h-1) => their phase-h-2 ds_reads completed (lgkmcnt
// before MFMA use precedes barrier arrival). vmcnt(8)+barrier at phase h =>
// all waves' unit-h loads landed before any wave's COMPUTE(h).
#define BPH 32  // KD/64
__global__ __launch_bounds__(512, 2) void gemm_i8_kernel(
    const int8_t* __restrict__ qa, const int8_t* __restrict__ qb,
    float* __restrict__ out, const unsigned int* __restrict__ sbits) {
  extern __shared__ __align__(16) int8_t L[];  // A: [0,64K), B: [64K,128K)

  // XCD supergroup: 1024 blocks = 8 XCDs x (4 brow x 32 bcol); A-panels L2-resident
  int bid = blockIdx.x;
  int xcd = bid & 7;
  int local = bid >> 3;               // 0..127
  int brow = xcd * 4 + (local & 3);   // 0..31
  int bcol = local >> 2;              // 0..31

  int t = threadIdx.x;
  int lane = t & 63;
  int w = t >> 6;            // 0..7
  int wr = (w >> 2) * 128;   // 0 | 128
  int wc = (w & 3) * 64;     // 0,64,128,192

  v4i acc[8][4] = {};

  const int8_t* ga = qa + (size_t)brow * 256 * KD;
  const int8_t* gb = qb + (size_t)bcol * 256 * KD;

  int srow = t >> 2;   // 0..127
  int sc = t & 3;

  auto STAGE = [&](int h) {  // stage k-chunk consumed at phase h into region h&3
    int reg = (h & 3) * 16384;
    int kcol = h * 64;
    #pragma unroll
    for (int j = 0; j < 2; ++j) {
      int row = j * 128 + srow;
      int gc = sc ^ ((row >> 1) & 3);   // pre-swizzled source, linear LDS dest
      gload_lds16(ga + (size_t)row * KD + kcol + gc * 16, L + reg + j * 8192 + t * 16);
    }
    #pragma unroll
    for (int j = 0; j < 2; ++j) {
      int row = j * 128 + srow;
      int gc = sc ^ ((row >> 1) & 3);
      gload_lds16(gb + (size_t)row * KD + kcol + gc * 16, L + 65536 + reg + j * 8192 + t * 16);
    }
  };

  auto COMPUTE = [&](int h) {
    const int8_t* LA = L + (h & 3) * 16384;
    const int8_t* LB = L + 65536 + (h & 3) * 16384;
    v4i aF[8], bF[4];
    #pragma unroll
    for (int n = 0; n < 4; ++n) {
      int row = wc + n * 16 + (lane & 15);
      int c = (lane >> 4) ^ ((row >> 1) & 3);
      bF[n] = *(const v4i*)(LB + row * 64 + c * 16);
    }
    #pragma unroll
    for (int m = 0; m < 8; ++m) {
      int row = wr + m * 16 + (lane & 15);
      int c = (lane >> 4) ^ ((row >> 1) & 3);
      aF[m] = *(const v4i*)(LA + row * 64 + c * 16);
    }
    __builtin_amdgcn_s_setprio(1);
    #pragma unroll
    for (int m = 0; m < 8; ++m)
      #pragma unroll
      for (int n = 0; n < 4; ++n)
        acc[m][n] = __builtin_amdgcn_mfma_i32_16x16x64_i8(aF[m], bF[n], acc[m][n], 0, 0, 0);
    __builtin_amdgcn_s_setprio(0);
  };

  STAGE(0);
  STAGE(1);
  for (int h = 0; h < BPH - 2; ++h) {
    STAGE(h + 2);
    asm volatile("s_waitcnt vmcnt(8)" ::: "memory");  // unit h landed; h+1,h+2 in flight
    __builtin_amdgcn_s_barrier();
    __builtin_amdgcn_sched_barrier(0);
    COMPUTE(h);
  }
  asm volatile("s_waitcnt vmcnt(4)" ::: "memory");
  __builtin_amdgcn_s_barrier();
  __builtin_amdgcn_sched_barrier(0);
  COMPUTE(BPH - 2);
  asm volatile("s_waitcnt vmcnt(0)" ::: "memory");
  __builtin_amdgcn_s_barrier();
  __builtin_amdgcn_sched_barrier(0);
  COMPUTE(BPH - 1);

  float s1 = __uint_as_float(sbits[0]);
  float s2 = __uint_as_float(sbits[1]);
  float scale = s1 * s2 / (127.0f * 127.0f);
  int orow = brow * 256 + wr + ((lane >> 4) * 4);
  int ocol = bcol * 256 + wc + (lane & 15);
  #pragma unroll
  for (int m = 0; m < 8; ++m)
    #pragma unroll
    for (int n = 0; n < 4; ++n)
      #pragma unroll
      for (int r = 0; r < 4; ++r)
        out[(size_t)(orow + m * 16 + r) * ND + (ocol + n * 16)] = (float)acc[m][n][r] * scale;
}

extern "C" void kernel_launch(void* const* d_in, const int* in_sizes, int n_in,
                              void* d_out, int out_size, void* d_ws, size_t ws_size,
                              hipStream_t stream) {
  const float* x1 = (const float*)d_in[0];
  const float* x2 = (const float*)d_in[1];
  float* out = (float*)d_out;
  uint8_t* ws = (uint8_t*)d_ws;

  unsigned int* sbits = (unsigned int*)ws;
  unsigned int* hist1 = (unsigned int*)(ws + 256);
  unsigned int* hist2 = (unsigned int*)(ws + 256 + 8192);
  int8_t* q1  = (int8_t*)(ws + 32768);
  int8_t* q2t = q1 + (size_t)MD * KD;

  const int n4_1 = MD * KD / 4;
  const int n4_2 = KD * ND / 4;

  // allow 128KB dynamic LDS (idempotent; not a stream op, graph-capture safe)
  hipFuncSetAttribute((const void*)gemm_i8_kernel,
                      hipFuncAttributeMaxDynamicSharedMemorySize, 131072);

  hipMemsetAsync(ws, 0, 32768, stream);
  absmax2_kernel<<<dim3(512, 2), 256, 0, stream>>>(x1, x2, sbits);
  quant_hist_kernel<<<1024, 256, 0, stream>>>(x1, q1, n4_1, sbits + 0, hist1);
  transq_kernel<<<dim3(ND / 64, KD / 64), 256, 0, stream>>>(x2, q2t, sbits + 1, hist2);
  finalize_kernel<<<2, 256, 0, stream>>>(hist1, hist2, out + (size_t)MD * ND);
  gemm_i8_kernel<<<1024, 512, 131072, stream>>>(q1, q2t, out, sbits);
}